// Round 1
// 203.916 us; speedup vs baseline: 1.0635x; 1.0635x over previous
//
#include <hip/hip_runtime.h>
#include <stdint.h>

typedef short s16x8 __attribute__((ext_vector_type(8)));
typedef short s16x4 __attribute__((ext_vector_type(4)));
typedef float f32x4 __attribute__((ext_vector_type(4)));

#define NPIX 65536
#define FEAT 224
#define PEND 6
#define HID  256

// fp32 -> bf16 round-to-nearest-even
__device__ __forceinline__ unsigned short f2bf(float x) {
  unsigned u = __float_as_uint(x);
  return (unsigned short)((u + 0x7FFFu + ((u >> 16) & 1u)) >> 16);
}
__device__ __forceinline__ float bf2f(unsigned short b) {
  return __uint_as_float(((unsigned)b) << 16);
}
__device__ __forceinline__ void glds16(const void* g, void* l) {
  __builtin_amdgcn_global_load_lds(
      (const __attribute__((address_space(1))) unsigned int*)g,
      (__attribute__((address_space(3))) unsigned int*)l, 16, 0, 0);
}

// ---- one-shot weight transpose+convert; accumulator zeroing folded in (was memset) ----
__global__ void cvtW_all(const float* __restrict__ W1, const float* __restrict__ W2,
                         const float* __restrict__ W3,
                         unsigned short* __restrict__ W1t, unsigned short* __restrict__ W2t,
                         unsigned short* __restrict__ W3t, float* __restrict__ gz) {
  int i = blockIdx.x * 256 + threadIdx.x;
  if (i < 57344) {                       // W1t: [256][224] from W1[224][256]
    int n = i / 224, k = i - n * 224;
    W1t[i] = f2bf(W1[k * 256 + n]);
  } else if (i < 122880) {               // W2t: [256][256] from W2[256][256]
    int i2 = i - 57344;
    int n = i2 >> 8, k = i2 & 255;
    W2t[i2] = f2bf(W2[k * 256 + n]);
  } else if (i < 188416) {               // W3t: [256(pad)][256] from W3[256][224]
    int i3 = i - 122880;
    int n = i3 >> 8, k = i3 & 255;
    W3t[i3] = (n < FEAT) ? f2bf(W3[k * FEAT + n]) : (unsigned short)0;
  } else if (i < 191104) {               // zero gsum+gsumY (2688 floats, contiguous)
    gz[i - 188416] = 0.f;
  }
}

// ---- fused: Y -> relu(YW1+b1) -> relu(hW2+b2) -> logits -> e=exp -> per-class sums ----
// 1024 blocks x 64 pixels, 64 KB LDS -> 2 blocks/CU.
// NEW (this round): double-buffered weight staging with ONE barrier per K-panel
// (2-phase: stage panel p+1 while computing p; barrier's implicit vmcnt(0) then waits
// on a load that had the whole compute phase to land). Prefetch chains across layer
// boundaries (panel stream s=0..22). Layer-1 A-tile: T14 split (global->regs early,
// convert+ds_write after MFMAs; reg loads issued BEFORE glds16 so their wait leaves
// the glds16s in flight). hS is [64][256] bf16 with XOR chunk swizzle
// (chunk ^= row&7 on 16B chunks) -- fits the 2nd Bs buffer in exactly 64 KB while
// keeping af reads bank-even (unpadded-unswizzled would 2x-serialize). Bs stays
// LINEAR (glds16 dest must be linear, rule #21). As overlays hS (dead in layer 1);
// red/cls overlay Bs (dead after layer 3). Classes precomputed once per block.
__global__ __launch_bounds__(256, 2)
void fused_mlp(const float* __restrict__ Y,
               const unsigned short* __restrict__ W1t,
               const unsigned short* __restrict__ W2t,
               const unsigned short* __restrict__ W3t,
               const float* __restrict__ b1, const float* __restrict__ b2,
               const float* __restrict__ b3, const float* __restrict__ ab,
               float* __restrict__ gsum, float* __restrict__ gsumY) {
  __shared__ __align__(16) unsigned short hS[64 * 256];   // 32768 B (swizzled chunks)
  __shared__ __align__(16) unsigned short Bs[2][8192];    // 32768 B (dbuf weights, linear)
  // overlays (time-disjoint):
  unsigned short* AsB = hS;                               // [2][64][36] = 9216 B, layer 1 only
  float* redE = (float*)&Bs[0][0];                        // 5376 B, after layer 3
  float* redY = redE + PEND * FEAT;                       // 5376 B
  unsigned short* clsS = (unsigned short*)(redY + PEND * FEAT);  // 128 B

  const int tid = threadIdx.x;
  const int wid = tid >> 6, lane = tid & 63;
  const int wm = wid >> 1, wn = wid & 1;
  const int mrow = lane & 15, quad = lane >> 4;
  const int brow = lane >> 2, bk8 = (lane & 3) * 8;
  const int arow = tid >> 2, aqtr = tid & 3;
  const long row0 = (long)blockIdx.x * 64;

  f32x4 acc[2][8];
  float4 pv0, pv1;

#define STAGE_W(s) do {                                                     \
    const unsigned short* Wp_; int ld_, k0_;                                \
    if ((s) < 7)       { Wp_ = W1t; ld_ = 224; k0_ = (s) * 32; }            \
    else if ((s) < 15) { Wp_ = W2t; ld_ = 256; k0_ = ((s) - 7) * 32; }      \
    else               { Wp_ = W3t; ld_ = 256; k0_ = ((s) - 15) * 32; }     \
    unsigned short* dst_ = &Bs[(s) & 1][wid * 2048];                        \
    _Pragma("unroll")                                                       \
    for (int c_ = 0; c_ < 4; c_++)                                          \
      glds16(Wp_ + (wid * 64 + c_ * 16 + brow) * ld_ + k0_ + bk8,           \
             dst_ + c_ * 512);                                              \
  } while (0)

#define LOADA(p) do {                                                       \
    const float* s_ = Y + (row0 + arow) * FEAT + (p) * 32 + aqtr * 8;       \
    pv0 = *(const float4*)s_; pv1 = *(const float4*)(s_ + 4);               \
  } while (0)

#define WRITEA(p) do {                                                      \
    unsigned short* d_ = AsB + ((p) & 1) * 2304 + arow * 36 + aqtr * 8;     \
    s16x4 lo_ = {(short)f2bf(pv0.x), (short)f2bf(pv0.y),                    \
                 (short)f2bf(pv0.z), (short)f2bf(pv0.w)};                   \
    s16x4 hi_ = {(short)f2bf(pv1.x), (short)f2bf(pv1.y),                    \
                 (short)f2bf(pv1.z), (short)f2bf(pv1.w)};                   \
    *(s16x4*)d_ = lo_; *(s16x4*)(d_ + 4) = hi_;                             \
  } while (0)

#define LOAD_B(buf)                                                         \
    _Pragma("unroll")                                                       \
    for (int j = 0; j < 8; j++)                                             \
      bfv[j] = *(const s16x8*)(&Bs[buf][(wn * 128 + j * 16 + mrow) * 32 + quad * 8]);

#define MFMA_ALL()                                                          \
    _Pragma("unroll")                                                       \
    for (int i = 0; i < 2; i++)                                             \
      _Pragma("unroll")                                                     \
      for (int j = 0; j < 8; j++)                                           \
        acc[i][j] = __builtin_amdgcn_mfma_f32_16x16x32_bf16(af[i], bfv[j], acc[i][j], 0, 0, 0);

#define ZERO_ACC()                                                          \
    _Pragma("unroll")                                                       \
    for (int i = 0; i < 2; i++)                                             \
      _Pragma("unroll")                                                     \
      for (int j = 0; j < 8; j++) acc[i][j] = {0.f, 0.f, 0.f, 0.f};

  // ================= layer 1: h1 = relu(Y @ W1 + b1), K=224 (panels 0..6) =================
  ZERO_ACC();
  LOADA(0); STAGE_W(0); WRITEA(0);
  __syncthreads();
  for (int p = 0; p < 7; p++) {
    if (p < 6) { LOADA(p + 1); STAGE_W(p + 1); }   // A-regs issued before glds16
    else       { STAGE_W(7); }                     // chain into layer-2 panel 0
    s16x8 af[2], bfv[8];
    const unsigned short* Ab = AsB + (p & 1) * 2304;
#pragma unroll
    for (int i = 0; i < 2; i++) {
      const unsigned short* pa = Ab + (wm * 32 + i * 16 + mrow) * 36 + quad * 8;
      s16x4 lo = *(const s16x4*)pa, hi = *(const s16x4*)(pa + 4);
      af[i] = __builtin_shufflevector(lo, hi, 0, 1, 2, 3, 4, 5, 6, 7);
    }
    LOAD_B(p & 1);
    MFMA_ALL();
    if (p < 6) WRITEA(p + 1);                      // convert after MFMAs (T14)
    __syncthreads();
  }
  // h1 epilogue -> swizzled hS (C/D: col=lane&15, row=quad*4+reg; m89/m91-verified)
#pragma unroll
  for (int j = 0; j < 8; j++) {
    int col = wn * 128 + j * 16 + mrow;
    float bb = b1[col];
    int cs = col >> 3, c7 = col & 7;
#pragma unroll
    for (int i = 0; i < 2; i++) {
      int r0 = wm * 32 + i * 16 + quad * 4;
#pragma unroll
      for (int r = 0; r < 4; r++) {
        int row = r0 + r;
        hS[row * 256 + ((cs ^ (row & 7)) << 3) + c7] = f2bf(fmaxf(acc[i][j][r] + bb, 0.f));
      }
    }
  }
  __syncthreads();

  // ================= layer 2: h2 = relu(h1 @ W2 + b2), K=256 (panels s=7..14) =================
  ZERO_ACC();
  for (int p = 0; p < 8; p++) {
    STAGE_W(p < 7 ? 8 + p : 15);                   // p=7 chains layer-3 panel 0
    const int k0 = p * 32, buf = (p + 1) & 1;
    s16x8 af[2], bfv[8];
#pragma unroll
    for (int i = 0; i < 2; i++) {
      int R = wm * 32 + i * 16 + mrow;
      int ch = (k0 >> 3) + quad;
      af[i] = *(const s16x8*)(hS + R * 256 + ((ch ^ (R & 7)) << 3));
    }
    LOAD_B(buf);
    MFMA_ALL();
    __syncthreads();
  }
  // h2 epilogue (overwrite h1)
#pragma unroll
  for (int j = 0; j < 8; j++) {
    int col = wn * 128 + j * 16 + mrow;
    float bb = b2[col];
    int cs = col >> 3, c7 = col & 7;
#pragma unroll
    for (int i = 0; i < 2; i++) {
      int r0 = wm * 32 + i * 16 + quad * 4;
#pragma unroll
      for (int r = 0; r < 4; r++) {
        int row = r0 + r;
        hS[row * 256 + ((cs ^ (row & 7)) << 3) + c7] = f2bf(fmaxf(acc[i][j][r] + bb, 0.f));
      }
    }
  }
  __syncthreads();

  // ========== layer 3: logits = h2 @ W3 + b3, K=256 (panels s=15..22) ==========
  ZERO_ACC();
  for (int p = 0; p < 8; p++) {
    if (p < 7) STAGE_W(16 + p);
    const int k0 = p * 32, buf = (p + 1) & 1;
    s16x8 af[2], bfv[8];
#pragma unroll
    for (int i = 0; i < 2; i++) {
      int R = wm * 32 + i * 16 + mrow;
      int ch = (k0 >> 3) + quad;
      af[i] = *(const s16x8*)(hS + R * 256 + ((ch ^ (R & 7)) << 3));
    }
    LOAD_B(buf);
    MFMA_ALL();
    __syncthreads();
  }
  // e = exp(logit) -> hS bf16 (no max-shift: |logit| small; r1-validated)
#pragma unroll
  for (int j = 0; j < 8; j++) {
    int col = wn * 128 + j * 16 + mrow;
    if (col < FEAT) {
      float bb = b3[col];
      int cs = col >> 3, c7 = col & 7;
#pragma unroll
      for (int i = 0; i < 2; i++) {
        int r0 = wm * 32 + i * 16 + quad * 4;
#pragma unroll
        for (int r = 0; r < 4; r++) {
          int row = r0 + r;
          hS[row * 256 + ((cs ^ (row & 7)) << 3) + c7] = f2bf(__expf(acc[i][j][r] + bb));
        }
      }
    }
  }
  // per-row argmax class, computed ONCE (64 threads), into Bs overlay (Bs now dead)
  if (tid < 64) {
    const float* a = ab + (row0 + tid) * PEND;
    float best = a[0]; int c = 0;
#pragma unroll
    for (int p = 1; p < PEND; p++) { float v = a[p]; if (v > best) { best = v; c = p; } }
    clsS[tid] = (unsigned short)c;
  }
  __syncthreads();

  // ================= reduce: per-(class,feature) {sum e, sum e*Y} =================
  const bool act = lane < 56;
  const int f0 = lane * 4;
  float accE[PEND][4], accY[PEND][4];
#pragma unroll
  for (int p = 0; p < PEND; p++)
#pragma unroll
    for (int i = 0; i < 4; i++) { accE[p][i] = 0.f; accY[p][i] = 0.f; }

#pragma unroll 4
  for (int r = wid; r < 64; r += 4) {
    int c = __builtin_amdgcn_readfirstlane((int)clsS[r]);
    if (act) {
      const unsigned short* pe = hS + r * 256 + (((f0 >> 3) ^ (r & 7)) << 3) + (f0 & 7);
      ushort4 e4 = *(const ushort4*)pe;
      float4 y4 = *(const float4*)(Y + (row0 + r) * FEAT + f0);
      float e[4] = {bf2f(e4.x), bf2f(e4.y), bf2f(e4.z), bf2f(e4.w)};
      float ey[4] = {e[0] * y4.x, e[1] * y4.y, e[2] * y4.z, e[3] * y4.w};
#define RK_CASE(P)                                                               \
      case P:                                                                    \
        _Pragma("unroll")                                                        \
        for (int i = 0; i < 4; i++) { accE[P][i] += e[i]; accY[P][i] += ey[i]; } \
        break;
      switch (c) {
        RK_CASE(0) RK_CASE(1) RK_CASE(2) RK_CASE(3) RK_CASE(4) RK_CASE(5)
      }
#undef RK_CASE
    }
  }

  // cross-wave combine, one wave at a time (plain LDS r/m/w, no atomics -- r2)
  for (int w = 0; w < 4; w++) {
    if (wid == w && act) {
#pragma unroll
      for (int p = 0; p < PEND; p++) {
        float4* pe = (float4*)(redE + p * FEAT + f0);
        float4* py = (float4*)(redY + p * FEAT + f0);
        float4 ve = {accE[p][0], accE[p][1], accE[p][2], accE[p][3]};
        float4 vy = {accY[p][0], accY[p][1], accY[p][2], accY[p][3]};
        if (w == 0) { *pe = ve; *py = vy; }
        else {
          float4 oe = *pe, oy = *py;
          oe.x += ve.x; oe.y += ve.y; oe.z += ve.z; oe.w += ve.w;
          oy.x += vy.x; oy.y += vy.y; oy.z += vy.z; oy.w += vy.w;
          *pe = oe; *py = oy;
        }
      }
    }
    __syncthreads();
  }

  for (int i = tid; i < PEND * FEAT; i += 256) {
    atomicAdd(&gsum[i], redE[i]);
    atomicAdd(&gsumY[i], redY[i]);
  }
#undef STAGE_W
#undef LOADA
#undef WRITEA
#undef LOAD_B
#undef MFMA_ALL
#undef ZERO_ACC
}

// ---- build M and Y_hat = abundance @ M ----
__global__ __launch_bounds__(256)
void yhat(const float* __restrict__ ab, const float* __restrict__ gsum,
          const float* __restrict__ gsumY, float* __restrict__ out) {
  constexpr int ROWS = 64;
  __shared__ float Ms[PEND * FEAT];
  __shared__ float aS[ROWS * PEND];
  const int tid = threadIdx.x;
  for (int i = tid; i < PEND * FEAT; i += 256) {
    float s = gsum[i];
    Ms[i] = (s > 0.f) ? gsumY[i] / s : 0.f;
  }
  const long n0 = (long)blockIdx.x * ROWS;
  for (int i = tid; i < ROWS * PEND; i += 256) aS[i] = ab[n0 * PEND + i];
  __syncthreads();

  const int wid = tid >> 6;
  const int lane = tid & 63;
  if (lane >= 56) return;
  const int f0 = lane * 4;
  float4 Mr[PEND];
#pragma unroll
  for (int p = 0; p < PEND; p++) Mr[p] = *(const float4*)(Ms + p * FEAT + f0);

  for (int r = wid; r < ROWS; r += 4) {
    float a[PEND];
#pragma unroll
    for (int p = 0; p < PEND; p++) a[p] = aS[r * PEND + p];
    float4 o = {0.f, 0.f, 0.f, 0.f};
#pragma unroll
    for (int p = 0; p < PEND; p++) {
      o.x += a[p] * Mr[p].x; o.y += a[p] * Mr[p].y;
      o.z += a[p] * Mr[p].z; o.w += a[p] * Mr[p].w;
    }
    *(float4*)(out + (n0 + r) * FEAT + f0) = o;
  }
}

extern "C" void kernel_launch(void* const* d_in, const int* in_sizes, int n_in,
                              void* d_out, int out_size, void* d_ws, size_t ws_size,
                              hipStream_t stream) {
  const float* ab = (const float*)d_in[0];
  const float* Y  = (const float*)d_in[1];
  const float* W1 = (const float*)d_in[2];
  const float* b1 = (const float*)d_in[3];
  const float* W2 = (const float*)d_in[4];
  const float* b2 = (const float*)d_in[5];
  const float* W3 = (const float*)d_in[6];
  const float* b3 = (const float*)d_in[7];
  float* out = (float*)d_out;

  char* ws = (char*)d_ws;
  const size_t oW1t  = 0;        // 256*224*2 = 114,688
  const size_t oW2t  = 114688;   // 256*256*2 = 131,072
  const size_t oW3t  = 245760;   // 256*256*2 = 131,072 (rows>=224 zero)
  const size_t osum  = 376832;   // gsum 5376 + gsumY 5376 (contiguous)

  unsigned short* W1t = (unsigned short*)(ws + oW1t);
  unsigned short* W2t = (unsigned short*)(ws + oW2t);
  unsigned short* W3t = (unsigned short*)(ws + oW3t);
  float* gsum  = (float*)(ws + osum);
  float* gsumY = (float*)(ws + osum + 5376);

  cvtW_all<<<747, 256, 0, stream>>>(W1, W2, W3, W1t, W2t, W3t, gsum);
  fused_mlp<<<1024, 256, 0, stream>>>(Y, W1t, W2t, W3t, b1, b2, b3, ab, gsum, gsumY);
  yhat<<<1024, 256, 0, stream>>>(ab, gsum, gsumY, out);
}

// Round 2
// 201.087 us; speedup vs baseline: 1.0785x; 1.0141x over previous
//
#include <hip/hip_runtime.h>
#include <stdint.h>

typedef short s16x8 __attribute__((ext_vector_type(8)));
typedef short s16x4 __attribute__((ext_vector_type(4)));
typedef float f32x4 __attribute__((ext_vector_type(4)));

#define NPIX 65536
#define FEAT 224
#define PEND 6
#define HID  256

// fp32 -> bf16 round-to-nearest-even
__device__ __forceinline__ unsigned short f2bf(float x) {
  unsigned u = __float_as_uint(x);
  return (unsigned short)((u + 0x7FFFu + ((u >> 16) & 1u)) >> 16);
}
__device__ __forceinline__ float bf2f(unsigned short b) {
  return __uint_as_float(((unsigned)b) << 16);
}
__device__ __forceinline__ void glds16(const void* g, void* l) {
  __builtin_amdgcn_global_load_lds(
      (const __attribute__((address_space(1))) unsigned int*)g,
      (__attribute__((address_space(3))) unsigned int*)l, 16, 0, 0);
}

// Counted vmcnt wait (T4): leaves the N youngest vmem ops in flight. The
// "memory" clobber pins ALL memory ops (loads, ds ops, glds16) on their side
// of the asm, so the count can never be broken by reordering.
#define WAITV(n) asm volatile("s_waitcnt vmcnt(" #n ")" ::: "memory")
// lgkm-only barrier: does NOT drain vmcnt (prefetched glds16 stay in flight).
#define BAR_LGKM() asm volatile("s_waitcnt lgkmcnt(0)\ns_barrier" ::: "memory")

// ---- one-shot weight transpose+convert; accumulator zeroing folded in ----
__global__ void cvtW_all(const float* __restrict__ W1, const float* __restrict__ W2,
                         const float* __restrict__ W3,
                         unsigned short* __restrict__ W1t, unsigned short* __restrict__ W2t,
                         unsigned short* __restrict__ W3t, float* __restrict__ gz) {
  int i = blockIdx.x * 256 + threadIdx.x;
  if (i < 57344) {                       // W1t: [256][224] from W1[224][256]
    int n = i / 224, k = i - n * 224;
    W1t[i] = f2bf(W1[k * 256 + n]);
  } else if (i < 122880) {               // W2t: [256][256] from W2[256][256]
    int i2 = i - 57344;
    int n = i2 >> 8, k = i2 & 255;
    W2t[i2] = f2bf(W2[k * 256 + n]);
  } else if (i < 188416) {               // W3t: [256(pad)][256] from W3[256][224]
    int i3 = i - 122880;
    int n = i3 >> 8, k = i3 & 255;
    W3t[i3] = (n < FEAT) ? f2bf(W3[k * FEAT + n]) : (unsigned short)0;
  } else if (i < 191104) {               // zero gsum+gsumY (2688 floats, contiguous)
    gz[i - 188416] = 0.f;
  }
}

// ---- fused: Y -> relu(YW1+b1) -> relu(hW2+b2) -> logits -> e=exp -> per-class sums ----
// 1024 blocks x 64 pixels, 64 KB LDS -> 2 blocks/CU.
// THIS ROUND: wave tile 64rows x 64cols (wave w owns cols w*64..+64). B-panel rows
// w*64..+64 are exactly the rows wave w stages itself via glds16 -> B is WAVE-PRIVATE:
// layers 2/3 run with ZERO barriers (hS read-only there); per-wave counted
// s_waitcnt vmcnt(4) replaces the per-panel __syncthreads (whose implicit vmcnt(0)
// drain was killing the double-buffer). Layer 1 keeps 7 barriers for the cross-wave
// As tile, but they are lgkm-only; glds16/Y-prefetch draining is per-wave WAITV(6)
// (count: younger-than-g(p) = lA(p+1)x2 + g(p+1)x4). 64x64 tiles also cut B-read
// duplication 2->1 (LDS reads -20%). s_setprio(1) around MFMA cluster (T5).
// hS [64][256] bf16, XOR chunk swizzle (chunk ^= row&7 on 16B chunks); Bs linear
// (glds16 dest must be linear, rule #21). As overlays hS; red/cls overlay Bs.
__global__ __launch_bounds__(256, 2)
void fused_mlp(const float* __restrict__ Y,
               const unsigned short* __restrict__ W1t,
               const unsigned short* __restrict__ W2t,
               const unsigned short* __restrict__ W3t,
               const float* __restrict__ b1, const float* __restrict__ b2,
               const float* __restrict__ b3, const float* __restrict__ ab,
               float* __restrict__ gsum, float* __restrict__ gsumY) {
  __shared__ __align__(16) unsigned short hS[64 * 256];   // 32768 B (swizzled chunks)
  __shared__ __align__(16) unsigned short Bs[2][8192];    // 32768 B (dbuf weights, linear)
  // overlays (time-disjoint):
  unsigned short* AsB = hS;                               // [2][64][36] = 9216 B, layer 1 only
  float* redE = (float*)&Bs[0][0];                        // 5376 B, after layer 3
  float* redY = redE + PEND * FEAT;                       // 5376 B
  unsigned short* clsS = (unsigned short*)(redY + PEND * FEAT);  // 128 B

  const int tid = threadIdx.x;
  const int wid = tid >> 6, lane = tid & 63;
  const int mrow = lane & 15, quad = lane >> 4;
  const int brow = lane >> 2, bk8 = (lane & 3) * 8;
  const int arow = tid >> 2, aqtr = tid & 3;
  const long row0 = (long)blockIdx.x * 64;

  f32x4 acc[4][4];
  float4 pv0, pv1;

#define STAGE_W(s) do {                                                     \
    const unsigned short* Wp_; int ld_, k0_;                                \
    if ((s) < 7)       { Wp_ = W1t; ld_ = 224; k0_ = (s) * 32; }            \
    else if ((s) < 15) { Wp_ = W2t; ld_ = 256; k0_ = ((s) - 7) * 32; }      \
    else               { Wp_ = W3t; ld_ = 256; k0_ = ((s) - 15) * 32; }     \
    unsigned short* dst_ = &Bs[(s) & 1][wid * 2048];                        \
    _Pragma("unroll")                                                       \
    for (int c_ = 0; c_ < 4; c_++)                                          \
      glds16(Wp_ + (wid * 64 + c_ * 16 + brow) * ld_ + k0_ + bk8,           \
             dst_ + c_ * 512);                                              \
  } while (0)

#define LOADA(p) do {                                                       \
    const float* s_ = Y + (row0 + arow) * FEAT + (p) * 32 + aqtr * 8;       \
    pv0 = *(const float4*)s_; pv1 = *(const float4*)(s_ + 4);               \
  } while (0)

#define WRITEA(p) do {                                                      \
    unsigned short* d_ = AsB + ((p) & 1) * 2304 + arow * 36 + aqtr * 8;     \
    s16x4 lo_ = {(short)f2bf(pv0.x), (short)f2bf(pv0.y),                    \
                 (short)f2bf(pv0.z), (short)f2bf(pv0.w)};                   \
    s16x4 hi_ = {(short)f2bf(pv1.x), (short)f2bf(pv1.y),                    \
                 (short)f2bf(pv1.z), (short)f2bf(pv1.w)};                   \
    *(s16x4*)d_ = lo_; *(s16x4*)(d_ + 4) = hi_;                             \
  } while (0)

#define LOAD_B(buf)                                                         \
    _Pragma("unroll")                                                       \
    for (int j = 0; j < 4; j++)                                             \
      bfv[j] = *(const s16x8*)(&Bs[buf][(wid * 64 + j * 16 + mrow) * 32 + quad * 8]);

#define MFMA_ALL() do {                                                     \
    __builtin_amdgcn_s_setprio(1);                                          \
    _Pragma("unroll")                                                       \
    for (int i = 0; i < 4; i++)                                             \
      _Pragma("unroll")                                                     \
      for (int j = 0; j < 4; j++)                                           \
        acc[i][j] = __builtin_amdgcn_mfma_f32_16x16x32_bf16(af[i], bfv[j], acc[i][j], 0, 0, 0); \
    __builtin_amdgcn_s_setprio(0);                                          \
  } while (0)

#define ZERO_ACC()                                                          \
    _Pragma("unroll")                                                       \
    for (int i = 0; i < 4; i++)                                             \
      _Pragma("unroll")                                                     \
      for (int j = 0; j < 4; j++) acc[i][j] = {0.f, 0.f, 0.f, 0.f};

  // ============ layer 1: h1 = relu(Y @ W1 + b1), K=224 (streams 0..6) ============
  ZERO_ACC();
  LOADA(0); STAGE_W(0); WRITEA(0);
  __syncthreads();                                   // full drain: g(s0) lands, As[0] visible
  for (int p = 0; p < 7; p++) {
    if (p < 6) { LOADA(p + 1); STAGE_W(p + 1); WAITV(6); }   // drains g(p), keeps lA+g(p+1)
    else       { STAGE_W(7);   WAITV(4); }                   // chain layer-2 panel 0
    s16x8 af[4], bfv[4];
    const unsigned short* Ab = AsB + (p & 1) * 2304;
#pragma unroll
    for (int i = 0; i < 4; i++) {
      const unsigned short* pa = Ab + (i * 16 + mrow) * 36 + quad * 8;
      s16x4 lo = *(const s16x4*)pa, hi = *(const s16x4*)(pa + 4);
      af[i] = __builtin_shufflevector(lo, hi, 0, 1, 2, 3, 4, 5, 6, 7);
    }
    LOAD_B(p & 1);
    MFMA_ALL();
    if (p < 6) WRITEA(p + 1);                        // convert after MFMAs (T14)
    BAR_LGKM();                                      // As visibility only; no vmcnt drain
  }
  // h1 epilogue -> swizzled hS (C/D: col=lane&15, row=quad*4+reg; m89/m91-verified)
#pragma unroll
  for (int j = 0; j < 4; j++) {
    int col = wid * 64 + j * 16 + mrow;
    float bb = b1[col];
    int cs = col >> 3, c7 = col & 7;
#pragma unroll
    for (int i = 0; i < 4; i++) {
#pragma unroll
      for (int r = 0; r < 4; r++) {
        int row = i * 16 + quad * 4 + r;
        hS[row * 256 + ((cs ^ (row & 7)) << 3) + c7] = f2bf(fmaxf(acc[i][j][r] + bb, 0.f));
      }
    }
  }
  BAR_LGKM();

  // ==== layer 2: h2 = relu(h1 @ W2 + b2), K=256 (streams 7..14) — BARRIER-FREE ====
  ZERO_ACC();
  for (int p = 0; p < 8; p++) {
    STAGE_W(8 + p);                                  // p=7 -> s15 (layer-3 panel 0)
    WAITV(4);                                        // drains g(7+p), keeps g(8+p)
    const int k0 = p * 32;
    s16x8 af[4], bfv[4];
#pragma unroll
    for (int i = 0; i < 4; i++) {
      int R = i * 16 + mrow;
      int ch = (k0 >> 3) + quad;
      af[i] = *(const s16x8*)(hS + R * 256 + ((ch ^ (R & 7)) << 3));
    }
    LOAD_B((7 + p) & 1);
    MFMA_ALL();
  }
  BAR_LGKM();                                        // all waves done reading hS
  // h2 epilogue (overwrite h1)
#pragma unroll
  for (int j = 0; j < 4; j++) {
    int col = wid * 64 + j * 16 + mrow;
    float bb = b2[col];
    int cs = col >> 3, c7 = col & 7;
#pragma unroll
    for (int i = 0; i < 4; i++) {
#pragma unroll
      for (int r = 0; r < 4; r++) {
        int row = i * 16 + quad * 4 + r;
        hS[row * 256 + ((cs ^ (row & 7)) << 3) + c7] = f2bf(fmaxf(acc[i][j][r] + bb, 0.f));
      }
    }
  }
  BAR_LGKM();

  // ==== layer 3: logits = h2 @ W3 + b3, K=256 (streams 15..22) — BARRIER-FREE ====
  ZERO_ACC();
  for (int p = 0; p < 8; p++) {
    if (p < 7) { STAGE_W(16 + p); WAITV(4); }
    else       { WAITV(0); }                         // last panel: drain own g(s22)
    const int k0 = p * 32;
    s16x8 af[4], bfv[4];
#pragma unroll
    for (int i = 0; i < 4; i++) {
      int R = i * 16 + mrow;
      int ch = (k0 >> 3) + quad;
      af[i] = *(const s16x8*)(hS + R * 256 + ((ch ^ (R & 7)) << 3));
    }
    LOAD_B((15 + p) & 1);
    MFMA_ALL();
  }
  BAR_LGKM();                                        // hS reads + Bs reads all done

  // e = exp(logit) -> hS bf16 (no max-shift: |logit| small; r1-validated)
#pragma unroll
  for (int j = 0; j < 4; j++) {
    int col = wid * 64 + j * 16 + mrow;
    if (col < FEAT) {
      float bb = b3[col];
      int cs = col >> 3, c7 = col & 7;
#pragma unroll
      for (int i = 0; i < 4; i++) {
#pragma unroll
        for (int r = 0; r < 4; r++) {
          int row = i * 16 + quad * 4 + r;
          hS[row * 256 + ((cs ^ (row & 7)) << 3) + c7] = f2bf(__expf(acc[i][j][r] + bb));
        }
      }
    }
  }
  // per-row argmax class, computed ONCE (64 threads), into Bs overlay (Bs now dead)
  if (tid < 64) {
    const float* a = ab + (row0 + tid) * PEND;
    float best = a[0]; int c = 0;
#pragma unroll
    for (int p = 1; p < PEND; p++) { float v = a[p]; if (v > best) { best = v; c = p; } }
    clsS[tid] = (unsigned short)c;
  }
  BAR_LGKM();

  // ================= reduce: per-(class,feature) {sum e, sum e*Y} =================
  const bool act = lane < 56;
  const int f0 = lane * 4;
  float accE[PEND][4], accY[PEND][4];
#pragma unroll
  for (int p = 0; p < PEND; p++)
#pragma unroll
    for (int i = 0; i < 4; i++) { accE[p][i] = 0.f; accY[p][i] = 0.f; }

#pragma unroll 4
  for (int r = wid; r < 64; r += 4) {
    int c = __builtin_amdgcn_readfirstlane((int)clsS[r]);
    if (act) {
      const unsigned short* pe = hS + r * 256 + (((f0 >> 3) ^ (r & 7)) << 3) + (f0 & 7);
      ushort4 e4 = *(const ushort4*)pe;
      float4 y4 = *(const float4*)(Y + (row0 + r) * FEAT + f0);
      float e[4] = {bf2f(e4.x), bf2f(e4.y), bf2f(e4.z), bf2f(e4.w)};
      float ey[4] = {e[0] * y4.x, e[1] * y4.y, e[2] * y4.z, e[3] * y4.w};
#define RK_CASE(P)                                                               \
      case P:                                                                    \
        _Pragma("unroll")                                                        \
        for (int i = 0; i < 4; i++) { accE[P][i] += e[i]; accY[P][i] += ey[i]; } \
        break;
      switch (c) {
        RK_CASE(0) RK_CASE(1) RK_CASE(2) RK_CASE(3) RK_CASE(4) RK_CASE(5)
      }
#undef RK_CASE
    }
  }

  // cross-wave combine, one wave at a time (plain LDS r/m/w, no atomics -- r2)
  for (int w = 0; w < 4; w++) {
    if (wid == w && act) {
#pragma unroll
      for (int p = 0; p < PEND; p++) {
        float4* pe = (float4*)(redE + p * FEAT + f0);
        float4* py = (float4*)(redY + p * FEAT + f0);
        float4 ve = {accE[p][0], accE[p][1], accE[p][2], accE[p][3]};
        float4 vy = {accY[p][0], accY[p][1], accY[p][2], accY[p][3]};
        if (w == 0) { *pe = ve; *py = vy; }
        else {
          float4 oe = *pe, oy = *py;
          oe.x += ve.x; oe.y += ve.y; oe.z += ve.z; oe.w += ve.w;
          oy.x += vy.x; oy.y += vy.y; oy.z += vy.z; oy.w += vy.w;
          *pe = oe; *py = oy;
        }
      }
    }
    __syncthreads();
  }

  for (int i = tid; i < PEND * FEAT; i += 256) {
    atomicAdd(&gsum[i], redE[i]);
    atomicAdd(&gsumY[i], redY[i]);
  }
#undef STAGE_W
#undef LOADA
#undef WRITEA
#undef LOAD_B
#undef MFMA_ALL
#undef ZERO_ACC
}

// ---- build M and Y_hat = abundance @ M ----
__global__ __launch_bounds__(256)
void yhat(const float* __restrict__ ab, const float* __restrict__ gsum,
          const float* __restrict__ gsumY, float* __restrict__ out) {
  constexpr int ROWS = 64;
  __shared__ float Ms[PEND * FEAT];
  __shared__ float aS[ROWS * PEND];
  const int tid = threadIdx.x;
  for (int i = tid; i < PEND * FEAT; i += 256) {
    float s = gsum[i];
    Ms[i] = (s > 0.f) ? gsumY[i] / s : 0.f;
  }
  const long n0 = (long)blockIdx.x * ROWS;
  for (int i = tid; i < ROWS * PEND; i += 256) aS[i] = ab[n0 * PEND + i];
  __syncthreads();

  const int wid = tid >> 6;
  const int lane = tid & 63;
  if (lane >= 56) return;
  const int f0 = lane * 4;
  float4 Mr[PEND];
#pragma unroll
  for (int p = 0; p < PEND; p++) Mr[p] = *(const float4*)(Ms + p * FEAT + f0);

  for (int r = wid; r < ROWS; r += 4) {
    float a[PEND];
#pragma unroll
    for (int p = 0; p < PEND; p++) a[p] = aS[r * PEND + p];
    float4 o = {0.f, 0.f, 0.f, 0.f};
#pragma unroll
    for (int p = 0; p < PEND; p++) {
      o.x += a[p] * Mr[p].x; o.y += a[p] * Mr[p].y;
      o.z += a[p] * Mr[p].z; o.w += a[p] * Mr[p].w;
    }
    *(float4*)(out + (n0 + r) * FEAT + f0) = o;
  }
}

extern "C" void kernel_launch(void* const* d_in, const int* in_sizes, int n_in,
                              void* d_out, int out_size, void* d_ws, size_t ws_size,
                              hipStream_t stream) {
  const float* ab = (const float*)d_in[0];
  const float* Y  = (const float*)d_in[1];
  const float* W1 = (const float*)d_in[2];
  const float* b1 = (const float*)d_in[3];
  const float* W2 = (const float*)d_in[4];
  const float* b2 = (const float*)d_in[5];
  const float* W3 = (const float*)d_in[6];
  const float* b3 = (const float*)d_in[7];
  float* out = (float*)d_out;

  char* ws = (char*)d_ws;
  const size_t oW1t  = 0;        // 256*224*2 = 114,688
  const size_t oW2t  = 114688;   // 256*256*2 = 131,072
  const size_t oW3t  = 245760;   // 256*256*2 = 131,072 (rows>=224 zero)
  const size_t osum  = 376832;   // gsum 5376 + gsumY 5376 (contiguous)

  unsigned short* W1t = (unsigned short*)(ws + oW1t);
  unsigned short* W2t = (unsigned short*)(ws + oW2t);
  unsigned short* W3t = (unsigned short*)(ws + oW3t);
  float* gsum  = (float*)(ws + osum);
  float* gsumY = (float*)(ws + osum + 5376);

  cvtW_all<<<747, 256, 0, stream>>>(W1, W2, W3, W1t, W2t, W3t, gsum);
  fused_mlp<<<1024, 256, 0, stream>>>(Y, W1t, W2t, W3t, b1, b2, b3, ab, gsum, gsumY);
  yhat<<<1024, 256, 0, stream>>>(ab, gsum, gsumY, out);
}